// Round 1
// baseline (68.573 us; speedup 1.0000x reference)
//
#include <hip/hip_runtime.h>
#include <math.h>

#define CHUNK 32
#define NPOS 60
#define TWO_PI_F 6.283185307179586f

__device__ __forceinline__ float bcastf(float v, int l) {
    return __builtin_bit_cast(float, __builtin_amdgcn_readlane(__builtin_bit_cast(int, v), l));
}

__global__ __launch_bounds__(256) void posloss_main(
    const float* __restrict__ pred, const float* __restrict__ target,
    float* __restrict__ partials, int B, int nchunks)
{
    const int tid  = threadIdx.x;
    const int lane = tid & 63;
    const int wv   = tid >> 6;
    const int wid  = (blockIdx.x * blockDim.x + tid) >> 6;
    const int nwaves = (gridDim.x * blockDim.x) >> 6;

    float a0 = 0.f, a1 = 0.f, a2 = 0.f, a3 = 0.f, a4 = 0.f;

    for (int c = wid; c < nchunks; c += nwaves) {
        const int base = c * CHUNK;

        // ---- prologue: lanes 0..31 compute per-row constants (32..63 duplicate) ----
        const int prow = base + (lane & 31);
        float r1 = 2.f, r3 = 2.f, r4 = 2.f, r5 = 1.f, al = 0.f;
        if (prow < B) {
            const float* pp = pred + (size_t)prow * 5;
            r1 = pp[0]; r3 = pp[1]; r4 = pp[2]; r5 = pp[3]; al = pp[4];
        }
        // L = [r1, 1, r3, r4]
        const float sumL = ((r1 + 1.0f) + r3) + r4;
        const float maxL = fmaxf(fmaxf(r1, 1.0f), fmaxf(r3, r4));
        const bool valid = (2.0f * maxL) < sumL;
        const bool c1 = ((r1 + 1.0f) - (r3 + r4)) > 0.0f;
        const bool c2 = (fabsf(r1 - 1.0f) - fabsf(r3 - r4)) >= 0.0f;
        const bool up = valid && c1 && c2;
        const bool lo = valid && (!c1) && (!c2);
        const bool bo = valid && c1 && (!c2);
        const float denom = 2.0f * r1;
        const float s34 = r3 + r4, d34 = r3 - r4;
        float argS = __fdiv_rn(__fsub_rn(__fadd_rn(__fmul_rn(r1, r1), 1.0f), __fmul_rn(s34, s34)), denom);
        float argD = __fdiv_rn(__fsub_rn(__fadd_rn(__fmul_rn(r1, r1), 1.0f), __fmul_rn(d34, d34)), denom);
        argS = (up || bo) ? argS : 0.0f;
        argD = (lo || bo) ? argD : 0.0f;
        argS = fminf(1.0f, fmaxf(-1.0f, argS));
        argD = fminf(1.0f, fmaxf(-1.0f, argD));
        const float acS = acosf(argS);
        const float acD = acosf(argD);
        float th2min = up ? (-acS) : ((lo || bo) ? acD : 0.0f);
        float th2max = (up || bo) ? acS : (lo ? __fsub_rn(TWO_PI_F, acD) : TWO_PI_F);
        if (!valid) { th2min = 0.0f; th2max = TWO_PI_F; }
        const float stp = __fdiv_rn(__fsub_rn(th2max, th2min), 59.0f);
        const int cat = (!valid) ? 0 : (up ? 1 : (lo ? 2 : (bo ? 3 : 4)));
        float sal, cal;
        sincosf(al, &sal, &cal);
        // k1 = (r1^2 + 1 + r3^2 - r4^2) - 2*r1*cos(th2); k2 = 2*r1*r3 - 2*r3*cos(th2); k3 = -2*r3*sin(th2)
        const float K1c = __fsub_rn(__fadd_rn(__fadd_rn(__fmul_rn(r1, r1), 1.0f), __fmul_rn(r3, r3)), __fmul_rn(r4, r4));
        const float K1m = 2.0f * r1;
        const float A2  = __fmul_rn(__fmul_rn(2.0f, r1), r3);
        const float B2  = __fmul_rn(2.0f, r3);

        // ---- inner: lane = position index, broadcast row consts via readlane ----
        const int rmax = (B - base) < CHUNK ? (B - base) : CHUNK;
        for (int r = 0; r < rmax; ++r) {
            const int catr = __builtin_amdgcn_readlane(cat, r);
            const size_t row = (size_t)(base + r);
            float tx = 0.0f, ty = 0.0f;
            if (lane < NPOS) {
                const float2 tv = *reinterpret_cast<const float2*>(target + row * (size_t)(2 * NPOS) + 2 * lane);
                tx = tv.x; ty = tv.y;
            }
            float contrib;
            if (catr != 0) {
                const float th2min_r = bcastf(th2min, r);
                const float stp_r = bcastf(stp, r);
                const float r5_r  = bcastf(r5, r);
                const float cal_r = bcastf(cal, r);
                const float sal_r = bcastf(sal, r);
                const float K1c_r = bcastf(K1c, r);
                const float K1m_r = bcastf(K1m, r);
                const float A2_r  = bcastf(A2, r);
                const float B2_r  = bcastf(B2, r);

                const float th2 = __fadd_rn(th2min_r, __fmul_rn(stp_r, (float)lane));
                float sth, cth;
                sincosf(th2, &sth, &cth);
                const float k1 = __fsub_rn(K1c_r, __fmul_rn(K1m_r, cth));
                const float k2 = __fsub_rn(A2_r, __fmul_rn(B2_r, cth));
                const float k3 = -__fmul_rn(B2_r, sth);
                const float a  = __fadd_rn(k1, k2);
                const float b  = __fmul_rn(-2.0f, k3);
                const float cc = __fsub_rn(k1, k2);
                const float disc = __fsub_rn(__fmul_rn(b, b), __fmul_rn(__fmul_rn(4.0f, a), cc));
                const bool bad = disc < 0.0f;
                const float D = sqrtf(bad ? 0.0f : disc);
                // th3 = 2*atan((D-b)/(2a)); use half-angle identity, division-free in u
                const float w = __fsub_rn(D, b);
                const float s = a + a;
                const float s2 = s * s, w2 = w * w;
                const float den = s2 + w2;
                const float rden = __builtin_amdgcn_rcpf(den);
                const float c3 = (s2 - w2) * rden;
                const float s3 = (2.0f * s * w) * rden;
                const float ca3 = cal_r * c3 - sal_r * s3;
                const float sa3 = sal_r * c3 + cal_r * s3;
                float px = __fadd_rn(cth, __fmul_rn(r5_r, ca3));
                float py = __fadd_rn(sth, __fmul_rn(r5_r, sa3));
                if (bad) { px = 0.0f; py = 0.0f; }
                const float dx = px - tx, dy = py - ty;
                contrib = (lane < NPOS) ? (dx * dx + dy * dy) : 0.0f;
            } else {
                contrib = tx * tx + ty * ty;  // invalid rows: sum target^2
            }
            if      (catr == 0) a0 += contrib;
            else if (catr == 1) a1 += contrib;
            else if (catr == 2) a2 += contrib;
            else if (catr == 3) a3 += contrib;
            else                a4 += contrib;
        }
    }

    // ---- wave reduce (64 lanes) ----
    for (int off = 32; off; off >>= 1) {
        a0 += __shfl_xor(a0, off);
        a1 += __shfl_xor(a1, off);
        a2 += __shfl_xor(a2, off);
        a3 += __shfl_xor(a3, off);
        a4 += __shfl_xor(a4, off);
    }
    __shared__ float red[4][5];
    if (lane == 0) {
        red[wv][0] = a0; red[wv][1] = a1; red[wv][2] = a2; red[wv][3] = a3; red[wv][4] = a4;
    }
    __syncthreads();
    if (tid < 5) {
        const float s = ((red[0][tid] + red[1][tid]) + red[2][tid]) + red[3][tid];
        partials[(size_t)tid * gridDim.x + blockIdx.x] = s;
    }
}

__global__ void posloss_reduce(const float* __restrict__ partials, float* __restrict__ out,
                               int nblocks, int B)
{
    const int w = threadIdx.x >> 6, lane = threadIdx.x & 63;
    if (w >= 5) return;
    double s = 0.0;
    for (int k = lane; k < nblocks; k += 64)
        s += (double)partials[(size_t)w * nblocks + k];
    for (int off = 32; off; off >>= 1) s += __shfl_down(s, off);
    if (lane == 0) out[w] = (float)(s / (double)B);
}

extern "C" void kernel_launch(void* const* d_in, const int* in_sizes, int n_in,
                              void* d_out, int out_size, void* d_ws, size_t ws_size,
                              hipStream_t stream) {
    (void)n_in; (void)out_size; (void)ws_size;
    const float* pred   = (const float*)d_in[0];
    const float* target = (const float*)d_in[1];
    float* out = (float*)d_out;
    float* partials = (float*)d_ws;
    const int B = in_sizes[0] / 5;
    const int nchunks = (B + CHUNK - 1) / CHUNK;
    const int nblocks = 2048;
    posloss_main<<<nblocks, 256, 0, stream>>>(pred, target, partials, B, nchunks);
    posloss_reduce<<<1, 320, 0, stream>>>(partials, out, nblocks, B);
}

// Round 2
// 61.107 us; speedup vs baseline: 1.1222x; 1.1222x over previous
//
#include <hip/hip_runtime.h>
#include <math.h>

#define CHUNK 32
#define NPOS 60
#define TWO_PI_F 6.283185307179586f
#define INV_TWO_PI_F 0.15915494309189535f

__device__ __forceinline__ float bcastf(float v, int l) {
    return __builtin_bit_cast(float, __builtin_amdgcn_readlane(__builtin_bit_cast(int, v), l));
}

// hardware sin/cos of (2*pi*rev), rev any finite value
__device__ __forceinline__ void hw_sincos_rev(float rev, float* s, float* c) {
    const float f = __builtin_amdgcn_fractf(rev);
    *s = __builtin_amdgcn_sinf(f);
    *c = __builtin_amdgcn_cosf(f);
}

__global__ __launch_bounds__(256) void posloss_main(
    const float* __restrict__ pred, const float* __restrict__ target,
    float* __restrict__ partials, int B, int nchunks)
{
    const int tid  = threadIdx.x;
    const int lane = tid & 63;
    const int wv   = tid >> 6;
    const int wid  = (blockIdx.x * blockDim.x + tid) >> 6;
    const int nwaves = (gridDim.x * blockDim.x) >> 6;

    float a0 = 0.f, a1 = 0.f, a2 = 0.f, a3 = 0.f, a4 = 0.f;

    for (int c = wid; c < nchunks; c += nwaves) {
        const int base = c * CHUNK;

        // ---- prologue: lanes 0..31 compute per-row constants (32..63 duplicate) ----
        const int prow = base + (lane & 31);
        float r1 = 2.f, r3 = 2.f, r4 = 2.f, r5 = 1.f, al = 0.f;
        if (prow < B) {
            const float* pp = pred + (size_t)prow * 5;
            r1 = pp[0]; r3 = pp[1]; r4 = pp[2]; r5 = pp[3]; al = pp[4];
        }
        // L = [r1, 1, r3, r4]
        const float sumL = ((r1 + 1.0f) + r3) + r4;
        const float maxL = fmaxf(fmaxf(r1, 1.0f), fmaxf(r3, r4));
        const bool valid = (2.0f * maxL) < sumL;
        const bool c1 = ((r1 + 1.0f) - (r3 + r4)) > 0.0f;
        const bool c2 = (fabsf(r1 - 1.0f) - fabsf(r3 - r4)) >= 0.0f;
        const bool up = valid && c1 && c2;
        const bool lo = valid && (!c1) && (!c2);
        const bool bo = valid && c1 && (!c2);
        const float denom = 2.0f * r1;
        const float s34 = r3 + r4, d34 = r3 - r4;
        float argS = __fdiv_rn(__fsub_rn(__fadd_rn(__fmul_rn(r1, r1), 1.0f), __fmul_rn(s34, s34)), denom);
        float argD = __fdiv_rn(__fsub_rn(__fadd_rn(__fmul_rn(r1, r1), 1.0f), __fmul_rn(d34, d34)), denom);
        argS = (up || bo) ? argS : 0.0f;
        argD = (lo || bo) ? argD : 0.0f;
        argS = fminf(1.0f, fmaxf(-1.0f, argS));
        argD = fminf(1.0f, fmaxf(-1.0f, argD));
        const float acS = acosf(argS);
        const float acD = acosf(argD);
        float th2min = up ? (-acS) : ((lo || bo) ? acD : 0.0f);
        float th2max = (up || bo) ? acS : (lo ? __fsub_rn(TWO_PI_F, acD) : TWO_PI_F);
        if (!valid) { th2min = 0.0f; th2max = TWO_PI_F; }
        const float stp = __fdiv_rn(__fsub_rn(th2max, th2min), 59.0f);
        // revolutions form for hw trig
        const float th2min_rev = th2min * INV_TWO_PI_F;
        const float stp_rev    = stp * INV_TWO_PI_F;
        const int cat = (!valid) ? 0 : (up ? 1 : (lo ? 2 : (bo ? 3 : 4)));
        float sal, cal;
        sincosf(al, &sal, &cal);
        // k1 = (r1^2+1+r3^2-r4^2) - 2*r1*cos(th2); k2 = 2*r1*r3 - 2*r3*cos(th2); k3 = -2*r3*sin(th2)
        const float K1c = __fsub_rn(__fadd_rn(__fadd_rn(__fmul_rn(r1, r1), 1.0f), __fmul_rn(r3, r3)), __fmul_rn(r4, r4));
        const float K1m = 2.0f * r1;
        const float A2  = __fmul_rn(__fmul_rn(2.0f, r1), r3);
        const float B2  = __fmul_rn(2.0f, r3);

        // ---- inner: lane = position index, broadcast row consts via readlane ----
        const int rmax = (B - base) < CHUNK ? (B - base) : CHUNK;
        for (int r = 0; r < rmax; ++r) {
            const int catr = __builtin_amdgcn_readlane(cat, r);
            const size_t row = (size_t)(base + r);
            float tx = 0.0f, ty = 0.0f;
            if (lane < NPOS) {
                const float2 tv = *reinterpret_cast<const float2*>(target + row * (size_t)(2 * NPOS) + 2 * lane);
                tx = tv.x; ty = tv.y;
            }
            float contrib;
            if (catr != 0) {
                const float th2min_rev_r = bcastf(th2min_rev, r);
                const float stp_rev_r = bcastf(stp_rev, r);
                const float r5_r  = bcastf(r5, r);
                const float cal_r = bcastf(cal, r);
                const float sal_r = bcastf(sal, r);
                const float K1c_r = bcastf(K1c, r);
                const float K1m_r = bcastf(K1m, r);
                const float A2_r  = bcastf(A2, r);
                const float B2_r  = bcastf(B2, r);

                const float rev = __fadd_rn(th2min_rev_r, __fmul_rn(stp_rev_r, (float)lane));
                float sth, cth;
                hw_sincos_rev(rev, &sth, &cth);
                const float k1 = __fsub_rn(K1c_r, __fmul_rn(K1m_r, cth));
                const float k2 = __fsub_rn(A2_r, __fmul_rn(B2_r, cth));
                const float k3 = -__fmul_rn(B2_r, sth);
                const float a  = __fadd_rn(k1, k2);
                const float b  = __fmul_rn(-2.0f, k3);
                const float cc = __fsub_rn(k1, k2);
                const float disc = __fsub_rn(__fmul_rn(b, b), __fmul_rn(__fmul_rn(4.0f, a), cc));
                const bool bad = disc < 0.0f;
                const float D = sqrtf(bad ? 0.0f : disc);
                // th3 = 2*atan((D-b)/(2a)); half-angle identity, division-free in the atan arg
                const float w = __fsub_rn(D, b);
                const float s = a + a;
                const float s2 = s * s, w2 = w * w;
                const float den = s2 + w2;
                const float rden = __builtin_amdgcn_rcpf(den);
                const float c3 = (s2 - w2) * rden;
                const float s3 = (2.0f * s * w) * rden;
                const float ca3 = cal_r * c3 - sal_r * s3;
                const float sa3 = sal_r * c3 + cal_r * s3;
                float px = __fadd_rn(cth, __fmul_rn(r5_r, ca3));
                float py = __fadd_rn(sth, __fmul_rn(r5_r, sa3));
                if (bad) { px = 0.0f; py = 0.0f; }
                const float dx = px - tx, dy = py - ty;
                contrib = (lane < NPOS) ? (dx * dx + dy * dy) : 0.0f;
            } else {
                contrib = tx * tx + ty * ty;  // invalid rows: sum target^2
            }
            if      (catr == 0) a0 += contrib;
            else if (catr == 1) a1 += contrib;
            else if (catr == 2) a2 += contrib;
            else if (catr == 3) a3 += contrib;
            else                a4 += contrib;
        }
    }

    // ---- wave reduce (64 lanes) ----
    for (int off = 32; off; off >>= 1) {
        a0 += __shfl_xor(a0, off);
        a1 += __shfl_xor(a1, off);
        a2 += __shfl_xor(a2, off);
        a3 += __shfl_xor(a3, off);
        a4 += __shfl_xor(a4, off);
    }
    __shared__ float red[4][5];
    if (lane == 0) {
        red[wv][0] = a0; red[wv][1] = a1; red[wv][2] = a2; red[wv][3] = a3; red[wv][4] = a4;
    }
    __syncthreads();
    if (tid < 5) {
        const float s = ((red[0][tid] + red[1][tid]) + red[2][tid]) + red[3][tid];
        partials[(size_t)tid * gridDim.x + blockIdx.x] = s;
    }
}

__global__ void posloss_reduce(const float* __restrict__ partials, float* __restrict__ out,
                               int nblocks, int B)
{
    const int w = threadIdx.x >> 6, lane = threadIdx.x & 63;
    if (w >= 5) return;
    double s = 0.0;
    for (int k = lane; k < nblocks; k += 64)
        s += (double)partials[(size_t)w * nblocks + k];
    for (int off = 32; off; off >>= 1) s += __shfl_down(s, off);
    if (lane == 0) out[w] = (float)(s / (double)B);
}

extern "C" void kernel_launch(void* const* d_in, const int* in_sizes, int n_in,
                              void* d_out, int out_size, void* d_ws, size_t ws_size,
                              hipStream_t stream) {
    (void)n_in; (void)out_size; (void)ws_size;
    const float* pred   = (const float*)d_in[0];
    const float* target = (const float*)d_in[1];
    float* out = (float*)d_out;
    float* partials = (float*)d_ws;
    const int B = in_sizes[0] / 5;
    const int nchunks = (B + CHUNK - 1) / CHUNK;
    const int nblocks = 2048;
    posloss_main<<<nblocks, 256, 0, stream>>>(pred, target, partials, B, nchunks);
    posloss_reduce<<<1, 320, 0, stream>>>(partials, out, nblocks, B);
}

// Round 3
// 52.435 us; speedup vs baseline: 1.3078x; 1.1654x over previous
//
#include <hip/hip_runtime.h>
#include <math.h>

#define CHUNK 32
#define GRP 8
#define NPOS 60
#define TWO_PI_F 6.283185307179586f
#define INV_TWO_PI_F 0.15915494309189535f

__device__ __forceinline__ float bcastf(float v, int l) {
    return __builtin_bit_cast(float, __builtin_amdgcn_readlane(__builtin_bit_cast(int, v), l));
}

__device__ __forceinline__ void hw_sincos_rev(float rev, float* s, float* c) {
    const float f = __builtin_amdgcn_fractf(rev);
    *s = __builtin_amdgcn_sinf(f);
    *c = __builtin_amdgcn_cosf(f);
}

__global__ __launch_bounds__(256) void posloss_main(
    const float* __restrict__ pred, const float* __restrict__ target,
    float* __restrict__ partials, int B, int nchunks)
{
    const int tid  = threadIdx.x;
    const int lane = tid & 63;
    const int wv   = tid >> 6;
    const int wid  = (blockIdx.x * blockDim.x + tid) >> 6;
    const int nwaves = (gridDim.x * blockDim.x) >> 6;

    float a0 = 0.f, a1 = 0.f, a2 = 0.f, a3 = 0.f, a4 = 0.f;

    for (int c = wid; c < nchunks; c += nwaves) {
        const int base = c * CHUNK;

        // ---- prologue: lanes 0..31 compute per-row constants (32..63 duplicate) ----
        const int prow = base + (lane & 31);
        float r1 = 2.f, r3 = 2.f, r4 = 2.f, r5 = 1.f, al = 0.f;
        if (prow < B) {
            const float* pp = pred + (size_t)prow * 5;
            r1 = pp[0]; r3 = pp[1]; r4 = pp[2]; r5 = pp[3]; al = pp[4];
        }
        const float sumL = ((r1 + 1.0f) + r3) + r4;
        const float maxL = fmaxf(fmaxf(r1, 1.0f), fmaxf(r3, r4));
        const bool valid = (2.0f * maxL) < sumL;
        const bool c1 = ((r1 + 1.0f) - (r3 + r4)) > 0.0f;
        const bool c2 = (fabsf(r1 - 1.0f) - fabsf(r3 - r4)) >= 0.0f;
        const bool up = valid && c1 && c2;
        const bool lo = valid && (!c1) && (!c2);
        const bool bo = valid && c1 && (!c2);
        const float denom = 2.0f * r1;
        const float s34 = r3 + r4, d34 = r3 - r4;
        float argS = __fdiv_rn(__fsub_rn(__fadd_rn(__fmul_rn(r1, r1), 1.0f), __fmul_rn(s34, s34)), denom);
        float argD = __fdiv_rn(__fsub_rn(__fadd_rn(__fmul_rn(r1, r1), 1.0f), __fmul_rn(d34, d34)), denom);
        argS = (up || bo) ? argS : 0.0f;
        argD = (lo || bo) ? argD : 0.0f;
        argS = fminf(1.0f, fmaxf(-1.0f, argS));
        argD = fminf(1.0f, fmaxf(-1.0f, argD));
        const float acS = acosf(argS);
        const float acD = acosf(argD);
        float th2min = up ? (-acS) : ((lo || bo) ? acD : 0.0f);
        float th2max = (up || bo) ? acS : (lo ? __fsub_rn(TWO_PI_F, acD) : TWO_PI_F);
        if (!valid) { th2min = 0.0f; th2max = TWO_PI_F; }
        const float stp = __fdiv_rn(__fsub_rn(th2max, th2min), 59.0f);
        const float th2min_rev = th2min * INV_TWO_PI_F;
        const float stp_rev    = stp * INV_TWO_PI_F;
        const int cat = (!valid) ? 0 : (up ? 1 : (lo ? 2 : (bo ? 3 : 4)));
        float sal, cal;
        sincosf(al, &sal, &cal);
        const float K1c = __fsub_rn(__fadd_rn(__fadd_rn(__fmul_rn(r1, r1), 1.0f), __fmul_rn(r3, r3)), __fmul_rn(r4, r4));
        const float K1m = 2.0f * r1;
        const float A2  = __fmul_rn(__fmul_rn(2.0f, r1), r3);
        const float B2  = __fmul_rn(2.0f, r3);

        const int rmax = (B - base) < CHUNK ? (B - base) : CHUNK;

        // ---- inner: groups of GRP rows; burst-load then compute (MLP) ----
        for (int r0 = 0; r0 < CHUNK; r0 += GRP) {
            float tx[GRP], ty[GRP];
            #pragma unroll
            for (int j = 0; j < GRP; ++j) {
                const int rr = r0 + j;
                float2 tv = make_float2(0.0f, 0.0f);
                if (rr < rmax && lane < NPOS) {
                    tv = *reinterpret_cast<const float2*>(
                        target + (size_t)(base + rr) * (size_t)(2 * NPOS) + 2 * lane);
                }
                tx[j] = tv.x; ty[j] = tv.y;
            }
            #pragma unroll
            for (int j = 0; j < GRP; ++j) {
                const int rr = r0 + j;
                if (rr >= rmax) continue;
                const int catr = __builtin_amdgcn_readlane(cat, rr);
                float contrib;
                if (catr != 0) {
                    const float th2min_rev_r = bcastf(th2min_rev, rr);
                    const float stp_rev_r = bcastf(stp_rev, rr);
                    const float r5_r  = bcastf(r5, rr);
                    const float cal_r = bcastf(cal, rr);
                    const float sal_r = bcastf(sal, rr);
                    const float K1c_r = bcastf(K1c, rr);
                    const float K1m_r = bcastf(K1m, rr);
                    const float A2_r  = bcastf(A2, rr);
                    const float B2_r  = bcastf(B2, rr);

                    const float rev = __fadd_rn(th2min_rev_r, __fmul_rn(stp_rev_r, (float)lane));
                    float sth, cth;
                    hw_sincos_rev(rev, &sth, &cth);
                    const float k1 = __fsub_rn(K1c_r, __fmul_rn(K1m_r, cth));
                    const float k2 = __fsub_rn(A2_r, __fmul_rn(B2_r, cth));
                    const float k3 = -__fmul_rn(B2_r, sth);
                    const float a  = __fadd_rn(k1, k2);
                    const float b  = __fmul_rn(-2.0f, k3);
                    const float cc = __fsub_rn(k1, k2);
                    const float disc = __fsub_rn(__fmul_rn(b, b), __fmul_rn(__fmul_rn(4.0f, a), cc));
                    const bool bad = disc < 0.0f;
                    const float D = sqrtf(bad ? 0.0f : disc);
                    const float w = __fsub_rn(D, b);
                    const float s = a + a;
                    const float s2 = s * s, w2 = w * w;
                    const float den = s2 + w2;
                    const float rden = __builtin_amdgcn_rcpf(den);
                    const float c3 = (s2 - w2) * rden;
                    const float s3 = (2.0f * s * w) * rden;
                    const float ca3 = cal_r * c3 - sal_r * s3;
                    const float sa3 = sal_r * c3 + cal_r * s3;
                    float px = __fadd_rn(cth, __fmul_rn(r5_r, ca3));
                    float py = __fadd_rn(sth, __fmul_rn(r5_r, sa3));
                    if (bad) { px = 0.0f; py = 0.0f; }
                    const float dx = px - tx[j], dy = py - ty[j];
                    contrib = (lane < NPOS) ? (dx * dx + dy * dy) : 0.0f;
                } else {
                    contrib = tx[j] * tx[j] + ty[j] * ty[j];
                }
                if      (catr == 0) a0 += contrib;
                else if (catr == 1) a1 += contrib;
                else if (catr == 2) a2 += contrib;
                else if (catr == 3) a3 += contrib;
                else                a4 += contrib;
            }
        }
    }

    // ---- wave reduce (64 lanes) ----
    for (int off = 32; off; off >>= 1) {
        a0 += __shfl_xor(a0, off);
        a1 += __shfl_xor(a1, off);
        a2 += __shfl_xor(a2, off);
        a3 += __shfl_xor(a3, off);
        a4 += __shfl_xor(a4, off);
    }
    __shared__ float red[4][5];
    if (lane == 0) {
        red[wv][0] = a0; red[wv][1] = a1; red[wv][2] = a2; red[wv][3] = a3; red[wv][4] = a4;
    }
    __syncthreads();
    if (tid < 5) {
        const float s = ((red[0][tid] + red[1][tid]) + red[2][tid]) + red[3][tid];
        partials[(size_t)tid * gridDim.x + blockIdx.x] = s;
    }
}

__global__ void posloss_reduce(const float* __restrict__ partials, float* __restrict__ out,
                               int nblocks, int B)
{
    const int w = threadIdx.x >> 6, lane = threadIdx.x & 63;
    if (w >= 5) return;
    double s0 = 0.0, s1 = 0.0, s2 = 0.0, s3 = 0.0;
    const float* p = partials + (size_t)w * nblocks;
    for (int k = lane; k + 192 < nblocks; k += 256) {
        s0 += (double)p[k];
        s1 += (double)p[k + 64];
        s2 += (double)p[k + 128];
        s3 += (double)p[k + 192];
    }
    double s = (s0 + s1) + (s2 + s3);
    for (int off = 32; off; off >>= 1) s += __shfl_down(s, off);
    if (lane == 0) out[w] = (float)(s / (double)B);
}

extern "C" void kernel_launch(void* const* d_in, const int* in_sizes, int n_in,
                              void* d_out, int out_size, void* d_ws, size_t ws_size,
                              hipStream_t stream) {
    (void)n_in; (void)out_size; (void)ws_size;
    const float* pred   = (const float*)d_in[0];
    const float* target = (const float*)d_in[1];
    float* out = (float*)d_out;
    float* partials = (float*)d_ws;
    const int B = in_sizes[0] / 5;
    const int nchunks = (B + CHUNK - 1) / CHUNK;
    const int nblocks = 2048;
    posloss_main<<<nblocks, 256, 0, stream>>>(pred, target, partials, B, nchunks);
    posloss_reduce<<<1, 320, 0, stream>>>(partials, out, nblocks, B);
}

// Round 4
// 50.596 us; speedup vs baseline: 1.3553x; 1.0363x over previous
//
#include <hip/hip_runtime.h>
#include <math.h>

#define CHUNK 32
#define GRP 8
#define NPOS 60
#define TWO_PI_F 6.283185307179586f
#define INV_TWO_PI_F 0.15915494309189535f
#define PI_F 3.14159265358979f

__device__ __forceinline__ float bcastf(float v, int l) {
    return __builtin_bit_cast(float, __builtin_amdgcn_readlane(__builtin_bit_cast(int, v), l));
}

// acos via Abramowitz-Stegun 4-term: max abs err ~6.7e-5 rad
__device__ __forceinline__ float acos_poly(float x) {
    const float ax = fabsf(x);
    const float s = __builtin_amdgcn_sqrtf(fmaxf(0.0f, 1.0f - ax));
    float p = fmaf(ax, -0.0187293f, 0.0742610f);
    p = fmaf(ax, p, -0.2121144f);
    p = fmaf(ax, p, 1.5707288f);
    const float r = s * p;
    return (x < 0.0f) ? (PI_F - r) : r;
}

__device__ __forceinline__ void hw_sincos_rev(float rev, float* s, float* c) {
    const float f = __builtin_amdgcn_fractf(rev);
    *s = __builtin_amdgcn_sinf(f);
    *c = __builtin_amdgcn_cosf(f);
}

__device__ __forceinline__ void load_burst(const float* __restrict__ target,
                                           int base, int r0, int rmax, int lane, bool inpos,
                                           float tx[GRP], float ty[GRP]) {
#pragma unroll
    for (int j = 0; j < GRP; ++j) {
        const int rr = r0 + j;
        float2 tv = make_float2(0.0f, 0.0f);
        if (rr < rmax && inpos) {
            tv = *reinterpret_cast<const float2*>(
                target + (size_t)(base + rr) * (size_t)(2 * NPOS) + 2 * lane);
        }
        tx[j] = tv.x; ty[j] = tv.y;
    }
}

__device__ __forceinline__ void compute_burst(
    int r0, int rmax, float flane, bool inpos,
    const float tx[GRP], const float ty[GRP],
    float th2min_rev, float stp_rev, float ca5, float sa5,
    float K1c, float K1m, float A2, float B2, int cat,
    float& a0, float& a1, float& a2, float& a3, float& a4)
{
#pragma unroll
    for (int j = 0; j < GRP; ++j) {
        const int rr = r0 + j;
        if (rr >= rmax) continue;
        const int catr = __builtin_amdgcn_readlane(cat, rr);
        float contrib;
        if (catr != 0) {
            const float rev0  = bcastf(th2min_rev, rr);
            const float stp_r = bcastf(stp_rev, rr);
            const float ca5_r = bcastf(ca5, rr);
            const float sa5_r = bcastf(sa5, rr);
            const float K1c_r = bcastf(K1c, rr);
            const float K1m_r = bcastf(K1m, rr);
            const float A2_r  = bcastf(A2, rr);
            const float B2_r  = bcastf(B2, rr);

            const float rev = fmaf(stp_r, flane, rev0);
            float sth, cth;
            hw_sincos_rev(rev, &sth, &cth);
            const float k1 = fmaf(-K1m_r, cth, K1c_r);
            const float k2 = fmaf(-B2_r, cth, A2_r);
            const float b  = 2.0f * (B2_r * sth);        // b = -2*k3, k3 = -B2*sth
            const float a  = k1 + k2;
            const float cc = k1 - k2;
            const float disc = fmaf(b, b, -4.0f * (a * cc));
            const bool bad = disc < 0.0f;
            const float D = __builtin_amdgcn_sqrtf(bad ? 0.0f : disc);
            const float w = D - b;
            const float s = a + a;
            const float s2 = s * s, w2 = w * w;
            const float rden = __builtin_amdgcn_rcpf(s2 + w2);
            const float c3 = (s2 - w2) * rden;
            const float s3 = (2.0f * s * w) * rden;
            float px = fmaf(ca5_r, c3, fmaf(-sa5_r, s3, cth));
            float py = fmaf(sa5_r, c3, fmaf(ca5_r, s3, sth));
            if (bad) { px = 0.0f; py = 0.0f; }
            const float dx = px - tx[j], dy = py - ty[j];
            contrib = inpos ? fmaf(dx, dx, dy * dy) : 0.0f;
        } else {
            contrib = fmaf(tx[j], tx[j], ty[j] * ty[j]);
        }
        if      (catr == 0) a0 += contrib;
        else if (catr == 1) a1 += contrib;
        else if (catr == 2) a2 += contrib;
        else if (catr == 3) a3 += contrib;
        else                a4 += contrib;
    }
}

__global__ __launch_bounds__(256) void posloss_main(
    const float* __restrict__ pred, const float* __restrict__ target,
    float* __restrict__ partials, int B, int nchunks)
{
    const int tid  = threadIdx.x;
    const int lane = tid & 63;
    const int wv   = tid >> 6;
    const int wid  = (blockIdx.x * blockDim.x + tid) >> 6;
    const bool inpos = lane < NPOS;
    const float flane = (float)lane;

    float a0 = 0.f, a1 = 0.f, a2 = 0.f, a3 = 0.f, a4 = 0.f;

    if (wid < nchunks) {
        const int base = wid * CHUNK;
        const int rmax = (B - base) < CHUNK ? (B - base) : CHUNK;

        // ---- issue pred loads ----
        const int prow = base + (lane & 31);
        float r1 = 2.f, r3 = 2.f, r4 = 2.f, r5 = 1.f, al = 0.f;
        if (prow < B) {
            const float* pp = pred + (size_t)prow * 5;
            r1 = pp[0]; r3 = pp[1]; r4 = pp[2]; r5 = pp[3]; al = pp[4];
        }

        // ---- issue first two target bursts (independent of pred) ----
        float txA[GRP], tyA[GRP], txB[GRP], tyB[GRP];
        load_burst(target, base, 0, rmax, lane, inpos, txA, tyA);
        load_burst(target, base, 8, rmax, lane, inpos, txB, tyB);

        // ---- prologue (libm-free) ----
        const float sumL = ((r1 + 1.0f) + r3) + r4;
        const float maxL = fmaxf(fmaxf(r1, 1.0f), fmaxf(r3, r4));
        const bool valid = (2.0f * maxL) < sumL;
        const bool c1 = ((r1 + 1.0f) - (r3 + r4)) > 0.0f;
        const bool c2 = (fabsf(r1 - 1.0f) - fabsf(r3 - r4)) >= 0.0f;
        const bool up = valid && c1 && c2;
        const bool lo = valid && (!c1) && (!c2);
        const bool bo = valid && c1 && (!c2);
        const float rdenom = __builtin_amdgcn_rcpf(2.0f * r1);
        const float s34 = r3 + r4, d34 = r3 - r4;
        const float r1sq1 = fmaf(r1, r1, 1.0f);
        float argS = (r1sq1 - s34 * s34) * rdenom;
        float argD = (r1sq1 - d34 * d34) * rdenom;
        argS = (up || bo) ? argS : 0.0f;
        argD = (lo || bo) ? argD : 0.0f;
        argS = fminf(1.0f, fmaxf(-1.0f, argS));
        argD = fminf(1.0f, fmaxf(-1.0f, argD));
        const float acS = acos_poly(argS);
        const float acD = acos_poly(argD);
        float th2min = up ? (-acS) : ((lo || bo) ? acD : 0.0f);
        float th2max = (up || bo) ? acS : (lo ? (TWO_PI_F - acD) : TWO_PI_F);
        if (!valid) { th2min = 0.0f; th2max = TWO_PI_F; }
        const float stp_rev    = (th2max - th2min) * (INV_TWO_PI_F / 59.0f);
        const float th2min_rev = th2min * INV_TWO_PI_F;
        const int cat = (!valid) ? 0 : (up ? 1 : (lo ? 2 : (bo ? 3 : 4)));
        float sal, cal;
        hw_sincos_rev(al * INV_TWO_PI_F, &sal, &cal);
        const float ca5 = r5 * cal, sa5 = r5 * sal;
        const float K1c = fmaf(r3, r3, r1sq1) - r4 * r4;
        const float K1m = 2.0f * r1;
        const float A2  = (2.0f * r1) * r3;
        const float B2  = 2.0f * r3;

        // ---- pipelined schedule: 2 bursts always in flight ----
        compute_burst(0, rmax, flane, inpos, txA, tyA, th2min_rev, stp_rev, ca5, sa5,
                      K1c, K1m, A2, B2, cat, a0, a1, a2, a3, a4);
        load_burst(target, base, 16, rmax, lane, inpos, txA, tyA);
        compute_burst(8, rmax, flane, inpos, txB, tyB, th2min_rev, stp_rev, ca5, sa5,
                      K1c, K1m, A2, B2, cat, a0, a1, a2, a3, a4);
        load_burst(target, base, 24, rmax, lane, inpos, txB, tyB);
        compute_burst(16, rmax, flane, inpos, txA, tyA, th2min_rev, stp_rev, ca5, sa5,
                      K1c, K1m, A2, B2, cat, a0, a1, a2, a3, a4);
        compute_burst(24, rmax, flane, inpos, txB, tyB, th2min_rev, stp_rev, ca5, sa5,
                      K1c, K1m, A2, B2, cat, a0, a1, a2, a3, a4);
    }

    // ---- wave reduce (64 lanes) ----
    for (int off = 32; off; off >>= 1) {
        a0 += __shfl_xor(a0, off);
        a1 += __shfl_xor(a1, off);
        a2 += __shfl_xor(a2, off);
        a3 += __shfl_xor(a3, off);
        a4 += __shfl_xor(a4, off);
    }
    __shared__ float red[4][5];
    if (lane == 0) {
        red[wv][0] = a0; red[wv][1] = a1; red[wv][2] = a2; red[wv][3] = a3; red[wv][4] = a4;
    }
    __syncthreads();
    if (tid < 5) {
        const float s = ((red[0][tid] + red[1][tid]) + red[2][tid]) + red[3][tid];
        partials[(size_t)tid * gridDim.x + blockIdx.x] = s;
    }
}

__global__ void posloss_reduce(const float* __restrict__ partials, float* __restrict__ out,
                               int nblocks, int B)
{
    const int w = threadIdx.x >> 6, lane = threadIdx.x & 63;
    if (w >= 5) return;
    double s0 = 0.0, s1 = 0.0, s2 = 0.0, s3 = 0.0;
    const float* p = partials + (size_t)w * nblocks;
    for (int k = lane; k + 192 < nblocks; k += 256) {
        s0 += (double)p[k];
        s1 += (double)p[k + 64];
        s2 += (double)p[k + 128];
        s3 += (double)p[k + 192];
    }
    double s = (s0 + s1) + (s2 + s3);
    for (int off = 32; off; off >>= 1) s += __shfl_down(s, off);
    if (lane == 0) out[w] = (float)(s / (double)B);
}

extern "C" void kernel_launch(void* const* d_in, const int* in_sizes, int n_in,
                              void* d_out, int out_size, void* d_ws, size_t ws_size,
                              hipStream_t stream) {
    (void)n_in; (void)out_size; (void)ws_size;
    const float* pred   = (const float*)d_in[0];
    const float* target = (const float*)d_in[1];
    float* out = (float*)d_out;
    float* partials = (float*)d_ws;
    const int B = in_sizes[0] / 5;
    const int nchunks = (B + CHUNK - 1) / CHUNK;
    const int nblocks = 2048;
    posloss_main<<<nblocks, 256, 0, stream>>>(pred, target, partials, B, nchunks);
    posloss_reduce<<<1, 320, 0, stream>>>(partials, out, nblocks, B);
}

// Round 5
// 49.458 us; speedup vs baseline: 1.3865x; 1.0230x over previous
//
#include <hip/hip_runtime.h>
#include <math.h>

#define CHUNK 32
#define NPOS 60
#define TWO_PI_F 6.283185307179586f
#define INV_TWO_PI_F 0.15915494309189535f
#define PI_F 3.14159265358979f

__device__ __forceinline__ float bcastf(float v, int l) {
    return __builtin_bit_cast(float, __builtin_amdgcn_readlane(__builtin_bit_cast(int, v), l));
}

// acos via Abramowitz-Stegun 4-term: max abs err ~6.7e-5 rad
__device__ __forceinline__ float acos_poly(float x) {
    const float ax = fabsf(x);
    const float s = __builtin_amdgcn_sqrtf(fmaxf(0.0f, 1.0f - ax));
    float p = fmaf(ax, -0.0187293f, 0.0742610f);
    p = fmaf(ax, p, -0.2121144f);
    p = fmaf(ax, p, 1.5707288f);
    const float r = s * p;
    return (x < 0.0f) ? (PI_F - r) : r;
}

__device__ __forceinline__ void hw_sincos_rev(float rev, float* s, float* c) {
    const float f = __builtin_amdgcn_fractf(rev);
    *s = __builtin_amdgcn_sinf(f);
    *c = __builtin_amdgcn_cosf(f);
}

// one row's squared-distance contribution; all per-row consts come in via readlane (SGPR)
__device__ __forceinline__ void row_acc(
    int rr, float txj, float tyj, float flane, bool inpos,
    float th2min_rev, float stp_rev, float ca5, float sa5,
    float K1c, float K1m, float A2, float B2, int cat,
    float& a0, float& a1, float& a2, float& a3, float& a4)
{
    const int catr = __builtin_amdgcn_readlane(cat, rr);
    float contrib;
    if (catr != 0) {
        const float rev0  = bcastf(th2min_rev, rr);
        const float stp_r = bcastf(stp_rev, rr);
        const float ca5_r = bcastf(ca5, rr);
        const float sa5_r = bcastf(sa5, rr);
        const float K1c_r = bcastf(K1c, rr);
        const float K1m_r = bcastf(K1m, rr);
        const float A2_r  = bcastf(A2, rr);
        const float B2_r  = bcastf(B2, rr);

        const float rev = fmaf(stp_r, flane, rev0);
        float sth, cth;
        hw_sincos_rev(rev, &sth, &cth);
        const float k1 = fmaf(-K1m_r, cth, K1c_r);
        const float k2 = fmaf(-B2_r, cth, A2_r);
        const float b  = 2.0f * (B2_r * sth);
        const float a  = k1 + k2;
        const float cc = k1 - k2;
        const float disc = fmaf(b, b, -4.0f * (a * cc));
        const bool bad = disc < 0.0f;
        const float D = __builtin_amdgcn_sqrtf(bad ? 0.0f : disc);
        const float w = D - b;
        const float s = a + a;
        const float s2 = s * s, w2 = w * w;
        const float rden = __builtin_amdgcn_rcpf(s2 + w2);
        const float c3 = (s2 - w2) * rden;
        const float s3 = (2.0f * s * w) * rden;
        float px = fmaf(ca5_r, c3, fmaf(-sa5_r, s3, cth));
        float py = fmaf(sa5_r, c3, fmaf(ca5_r, s3, sth));
        if (bad) { px = 0.0f; py = 0.0f; }
        const float dx = px - txj, dy = py - tyj;
        contrib = inpos ? fmaf(dx, dx, dy * dy) : 0.0f;
    } else {
        contrib = fmaf(txj, txj, tyj * tyj);
    }
    if      (catr == 0) a0 += contrib;
    else if (catr == 1) a1 += contrib;
    else if (catr == 2) a2 += contrib;
    else if (catr == 3) a3 += contrib;
    else                a4 += contrib;
}

// 8 float2 loads, all named scalars (NO arrays -> stays in VGPRs)
#define LOADB(P, r0)                                                                   \
    do {                                                                               \
        float2 _v;                                                                     \
        _v = ldt(target, base, (r0) + 0, lane, inpos); P##x0 = _v.x; P##y0 = _v.y;     \
        _v = ldt(target, base, (r0) + 1, lane, inpos); P##x1 = _v.x; P##y1 = _v.y;     \
        _v = ldt(target, base, (r0) + 2, lane, inpos); P##x2 = _v.x; P##y2 = _v.y;     \
        _v = ldt(target, base, (r0) + 3, lane, inpos); P##x3 = _v.x; P##y3 = _v.y;     \
        _v = ldt(target, base, (r0) + 4, lane, inpos); P##x4 = _v.x; P##y4 = _v.y;     \
        _v = ldt(target, base, (r0) + 5, lane, inpos); P##x5 = _v.x; P##y5 = _v.y;     \
        _v = ldt(target, base, (r0) + 6, lane, inpos); P##x6 = _v.x; P##y6 = _v.y;     \
        _v = ldt(target, base, (r0) + 7, lane, inpos); P##x7 = _v.x; P##y7 = _v.y;     \
    } while (0)

#define COMPUTEB(P, r0)                                                                          \
    do {                                                                                         \
        row_acc((r0) + 0, P##x0, P##y0, flane, inpos, th2min_rev, stp_rev, ca5, sa5,             \
                K1c, K1m, A2, B2, cat, a0, a1, a2, a3, a4);                                      \
        row_acc((r0) + 1, P##x1, P##y1, flane, inpos, th2min_rev, stp_rev, ca5, sa5,             \
                K1c, K1m, A2, B2, cat, a0, a1, a2, a3, a4);                                      \
        row_acc((r0) + 2, P##x2, P##y2, flane, inpos, th2min_rev, stp_rev, ca5, sa5,             \
                K1c, K1m, A2, B2, cat, a0, a1, a2, a3, a4);                                      \
        row_acc((r0) + 3, P##x3, P##y3, flane, inpos, th2min_rev, stp_rev, ca5, sa5,             \
                K1c, K1m, A2, B2, cat, a0, a1, a2, a3, a4);                                      \
        row_acc((r0) + 4, P##x4, P##y4, flane, inpos, th2min_rev, stp_rev, ca5, sa5,             \
                K1c, K1m, A2, B2, cat, a0, a1, a2, a3, a4);                                      \
        row_acc((r0) + 5, P##x5, P##y5, flane, inpos, th2min_rev, stp_rev, ca5, sa5,             \
                K1c, K1m, A2, B2, cat, a0, a1, a2, a3, a4);                                      \
        row_acc((r0) + 6, P##x6, P##y6, flane, inpos, th2min_rev, stp_rev, ca5, sa5,             \
                K1c, K1m, A2, B2, cat, a0, a1, a2, a3, a4);                                      \
        row_acc((r0) + 7, P##x7, P##y7, flane, inpos, th2min_rev, stp_rev, ca5, sa5,             \
                K1c, K1m, A2, B2, cat, a0, a1, a2, a3, a4);                                      \
    } while (0)

__device__ __forceinline__ float2 ldt(const float* __restrict__ target,
                                      int base, int rr, int lane, bool inpos) {
    float2 tv = make_float2(0.0f, 0.0f);
    if (inpos) {
        tv = *reinterpret_cast<const float2*>(
            target + (size_t)(base + rr) * (size_t)(2 * NPOS) + 2 * lane);
    }
    return tv;
}

__global__ __launch_bounds__(256) void posloss_main(
    const float* __restrict__ pred, const float* __restrict__ target,
    float* __restrict__ partials, int B, int nchunks)
{
    const int tid  = threadIdx.x;
    const int lane = tid & 63;
    const int wv   = tid >> 6;
    const int wid  = (blockIdx.x * blockDim.x + tid) >> 6;
    const bool inpos = lane < NPOS;
    const float flane = (float)lane;

    float a0 = 0.f, a1 = 0.f, a2 = 0.f, a3 = 0.f, a4 = 0.f;

    if (wid < nchunks) {
        const int base = wid * CHUNK;
        const int rmax = (B - base) < CHUNK ? (B - base) : CHUNK;

        // ---- issue pred loads ----
        const int prow = base + (lane & 31);
        float r1 = 2.f, r3 = 2.f, r4 = 2.f, r5 = 1.f, al = 0.f;
        if (prow < B) {
            const float* pp = pred + (size_t)prow * 5;
            r1 = pp[0]; r3 = pp[1]; r4 = pp[2]; r5 = pp[3]; al = pp[4];
        }

        // ---- burst registers: 32 named scalars ----
        float Ax0,Ay0,Ax1,Ay1,Ax2,Ay2,Ax3,Ay3,Ax4,Ay4,Ax5,Ay5,Ax6,Ay6,Ax7,Ay7;
        float Bx0,By0,Bx1,By1,Bx2,By2,Bx3,By3,Bx4,By4,Bx5,By5,Bx6,By6,Bx7,By7;

        if (rmax == CHUNK) {
            // ---- issue first two bursts (independent of pred math) ----
            LOADB(A, 0);
            LOADB(B, 8);

            // ---- prologue (libm-free) ----
            const float sumL = ((r1 + 1.0f) + r3) + r4;
            const float maxL = fmaxf(fmaxf(r1, 1.0f), fmaxf(r3, r4));
            const bool valid = (2.0f * maxL) < sumL;
            const bool c1 = ((r1 + 1.0f) - (r3 + r4)) > 0.0f;
            const bool c2 = (fabsf(r1 - 1.0f) - fabsf(r3 - r4)) >= 0.0f;
            const bool up = valid && c1 && c2;
            const bool lo = valid && (!c1) && (!c2);
            const bool bo = valid && c1 && (!c2);
            const float rdenom = __builtin_amdgcn_rcpf(2.0f * r1);
            const float s34 = r3 + r4, d34 = r3 - r4;
            const float r1sq1 = fmaf(r1, r1, 1.0f);
            float argS = (r1sq1 - s34 * s34) * rdenom;
            float argD = (r1sq1 - d34 * d34) * rdenom;
            argS = (up || bo) ? argS : 0.0f;
            argD = (lo || bo) ? argD : 0.0f;
            argS = fminf(1.0f, fmaxf(-1.0f, argS));
            argD = fminf(1.0f, fmaxf(-1.0f, argD));
            const float acS = acos_poly(argS);
            const float acD = acos_poly(argD);
            float th2min = up ? (-acS) : ((lo || bo) ? acD : 0.0f);
            float th2max = (up || bo) ? acS : (lo ? (TWO_PI_F - acD) : TWO_PI_F);
            if (!valid) { th2min = 0.0f; th2max = TWO_PI_F; }
            const float stp_rev    = (th2max - th2min) * (INV_TWO_PI_F / 59.0f);
            const float th2min_rev = th2min * INV_TWO_PI_F;
            const int cat = (!valid) ? 0 : (up ? 1 : (lo ? 2 : (bo ? 3 : 4)));
            float sal, cal;
            hw_sincos_rev(al * INV_TWO_PI_F, &sal, &cal);
            const float ca5 = r5 * cal, sa5 = r5 * sal;
            const float K1c = fmaf(r3, r3, r1sq1) - r4 * r4;
            const float K1m = 2.0f * r1;
            const float A2  = (2.0f * r1) * r3;
            const float B2  = 2.0f * r3;

            // ---- pipelined: 2 bursts in flight ----
            COMPUTEB(A, 0);
            LOADB(A, 16);
            COMPUTEB(B, 8);
            LOADB(B, 24);
            COMPUTEB(A, 16);
            COMPUTEB(B, 24);
        } else {
            // ---- rare partial-chunk fallback: rolled, guarded ----
            const float sumL = ((r1 + 1.0f) + r3) + r4;
            const float maxL = fmaxf(fmaxf(r1, 1.0f), fmaxf(r3, r4));
            const bool valid = (2.0f * maxL) < sumL;
            const bool c1 = ((r1 + 1.0f) - (r3 + r4)) > 0.0f;
            const bool c2 = (fabsf(r1 - 1.0f) - fabsf(r3 - r4)) >= 0.0f;
            const bool up = valid && c1 && c2;
            const bool lo = valid && (!c1) && (!c2);
            const bool bo = valid && c1 && (!c2);
            const float rdenom = __builtin_amdgcn_rcpf(2.0f * r1);
            const float s34 = r3 + r4, d34 = r3 - r4;
            const float r1sq1 = fmaf(r1, r1, 1.0f);
            float argS = (r1sq1 - s34 * s34) * rdenom;
            float argD = (r1sq1 - d34 * d34) * rdenom;
            argS = (up || bo) ? argS : 0.0f;
            argD = (lo || bo) ? argD : 0.0f;
            argS = fminf(1.0f, fmaxf(-1.0f, argS));
            argD = fminf(1.0f, fmaxf(-1.0f, argD));
            const float acS = acos_poly(argS);
            const float acD = acos_poly(argD);
            float th2min = up ? (-acS) : ((lo || bo) ? acD : 0.0f);
            float th2max = (up || bo) ? acS : (lo ? (TWO_PI_F - acD) : TWO_PI_F);
            if (!valid) { th2min = 0.0f; th2max = TWO_PI_F; }
            const float stp_rev    = (th2max - th2min) * (INV_TWO_PI_F / 59.0f);
            const float th2min_rev = th2min * INV_TWO_PI_F;
            const int cat = (!valid) ? 0 : (up ? 1 : (lo ? 2 : (bo ? 3 : 4)));
            float sal, cal;
            hw_sincos_rev(al * INV_TWO_PI_F, &sal, &cal);
            const float ca5 = r5 * cal, sa5 = r5 * sal;
            const float K1c = fmaf(r3, r3, r1sq1) - r4 * r4;
            const float K1m = 2.0f * r1;
            const float A2  = (2.0f * r1) * r3;
            const float B2  = 2.0f * r3;

            for (int rr = 0; rr < rmax; ++rr) {
                const float2 tv = ldt(target, base, rr, lane, inpos);
                row_acc(rr, tv.x, tv.y, flane, inpos, th2min_rev, stp_rev, ca5, sa5,
                        K1c, K1m, A2, B2, cat, a0, a1, a2, a3, a4);
            }
        }
    }

    // ---- wave reduce (64 lanes) ----
    for (int off = 32; off; off >>= 1) {
        a0 += __shfl_xor(a0, off);
        a1 += __shfl_xor(a1, off);
        a2 += __shfl_xor(a2, off);
        a3 += __shfl_xor(a3, off);
        a4 += __shfl_xor(a4, off);
    }
    __shared__ float red[4][5];
    if (lane == 0) {
        red[wv][0] = a0; red[wv][1] = a1; red[wv][2] = a2; red[wv][3] = a3; red[wv][4] = a4;
    }
    __syncthreads();
    if (tid < 5) {
        const float s = ((red[0][tid] + red[1][tid]) + red[2][tid]) + red[3][tid];
        partials[(size_t)tid * gridDim.x + blockIdx.x] = s;
    }
}

__global__ void posloss_reduce(const float* __restrict__ partials, float* __restrict__ out,
                               int nblocks, int B)
{
    const int w = threadIdx.x >> 6, lane = threadIdx.x & 63;
    if (w >= 5) return;
    double s0 = 0.0, s1 = 0.0, s2 = 0.0, s3 = 0.0;
    const float* p = partials + (size_t)w * nblocks;
    for (int k = lane; k + 192 < nblocks; k += 256) {
        s0 += (double)p[k];
        s1 += (double)p[k + 64];
        s2 += (double)p[k + 128];
        s3 += (double)p[k + 192];
    }
    double s = (s0 + s1) + (s2 + s3);
    for (int off = 32; off; off >>= 1) s += __shfl_down(s, off);
    if (lane == 0) out[w] = (float)(s / (double)B);
}

extern "C" void kernel_launch(void* const* d_in, const int* in_sizes, int n_in,
                              void* d_out, int out_size, void* d_ws, size_t ws_size,
                              hipStream_t stream) {
    (void)n_in; (void)out_size; (void)ws_size;
    const float* pred   = (const float*)d_in[0];
    const float* target = (const float*)d_in[1];
    float* out = (float*)d_out;
    float* partials = (float*)d_ws;
    const int B = in_sizes[0] / 5;
    const int nchunks = (B + CHUNK - 1) / CHUNK;
    const int nblocks = 2048;
    posloss_main<<<nblocks, 256, 0, stream>>>(pred, target, partials, B, nchunks);
    posloss_reduce<<<1, 320, 0, stream>>>(partials, out, nblocks, B);
}

// Round 6
// 45.405 us; speedup vs baseline: 1.5102x; 1.0893x over previous
//
#include <hip/hip_runtime.h>
#include <math.h>

#define CHUNK 32
#define NPOS 60
#define TWO_PI_F 6.283185307179586f
#define INV_TWO_PI_F 0.15915494309189535f
#define PI_F 3.14159265358979f

__device__ __forceinline__ float bcastf(float v, int l) {
    return __builtin_bit_cast(float, __builtin_amdgcn_readlane(__builtin_bit_cast(int, v), l));
}

// acos via Abramowitz-Stegun 4-term: max abs err ~6.7e-5 rad
__device__ __forceinline__ float acos_poly(float x) {
    const float ax = fabsf(x);
    const float s = __builtin_amdgcn_sqrtf(fmaxf(0.0f, 1.0f - ax));
    float p = fmaf(ax, -0.0187293f, 0.0742610f);
    p = fmaf(ax, p, -0.2121144f);
    p = fmaf(ax, p, 1.5707288f);
    const float r = s * p;
    return (x < 0.0f) ? (PI_F - r) : r;
}

__device__ __forceinline__ void hw_sincos_rev(float rev, float* s, float* c) {
    const float f = __builtin_amdgcn_fractf(rev);
    *s = __builtin_amdgcn_sinf(f);
    *c = __builtin_amdgcn_cosf(f);
}

// One row's contribution. Fully branchless; per-row consts arrive via readlane (SGPR).
// a = P - Q*cth ; cc = R - S*cth ; b = Bb*sth   (pre-folded algebra)
__device__ __forceinline__ void row_acc(
    int rr, float txj, float tyj, float flane, bool inpos,
    float th2min_rev, float stp_rev, float ca5, float sa5,
    float P, float Q, float R, float S, float Bb, int cat,
    float& a0, float& a1, float& a2, float& a3, float& a4)
{
    const int catr    = __builtin_amdgcn_readlane(cat, rr);
    const float rev0  = bcastf(th2min_rev, rr);
    const float stp_r = bcastf(stp_rev, rr);
    const float ca5_r = bcastf(ca5, rr);
    const float sa5_r = bcastf(sa5, rr);
    const float P_r   = bcastf(P, rr);
    const float Q_r   = bcastf(Q, rr);
    const float R_r   = bcastf(R, rr);
    const float S_r   = bcastf(S, rr);
    const float Bb_r  = bcastf(Bb, rr);

    const float rev = fmaf(stp_r, flane, rev0);
    float sth, cth;
    hw_sincos_rev(rev, &sth, &cth);
    const float a  = fmaf(-Q_r, cth, P_r);
    const float cc = fmaf(-S_r, cth, R_r);
    const float b  = Bb_r * sth;
    const float t  = a * cc;
    const float bb = b * b;
    const float disc = fmaf(-4.0f, t, bb);
    const bool bad = disc < 0.0f;
    const float D = __builtin_amdgcn_sqrtf(fmaxf(disc, 0.0f));
    const float w = D - b;
    const float s = a + a;
    const float s2 = s * s, w2 = w * w;
    const float rden = __builtin_amdgcn_rcpf(s2 + w2);
    const float c3 = (s2 - w2) * rden;
    const float sw = s * w;
    const float s3 = (sw + sw) * rden;
    float px = fmaf(ca5_r, c3, fmaf(-sa5_r, s3, cth));
    float py = fmaf(sa5_r, c3, fmaf(ca5_r, s3, sth));
    px = bad ? 0.0f : px;
    py = bad ? 0.0f : py;
    const float dx = px - txj, dy = py - tyj;
    float ch = fmaf(dx, dx, dy * dy);
    ch = inpos ? ch : 0.0f;
    const float c0 = fmaf(txj, txj, tyj * tyj);
    a0 += (catr == 0) ? c0 : 0.0f;
    a1 += (catr == 1) ? ch : 0.0f;
    a2 += (catr == 2) ? ch : 0.0f;
    a3 += (catr == 3) ? ch : 0.0f;
    a4 += (catr == 4) ? ch : 0.0f;
}

__device__ __forceinline__ float2 ldt(const float* __restrict__ target,
                                      int base, int rr, int lane, bool inpos) {
    float2 tv = make_float2(0.0f, 0.0f);
    if (inpos) {
        tv = *reinterpret_cast<const float2*>(
            target + (size_t)(base + rr) * (size_t)(2 * NPOS) + 2 * lane);
    }
    return tv;
}

// 8 float2 loads, all named scalars (NO arrays -> stays in VGPRs)
#define LOADB(Pfx, r0)                                                                     \
    do {                                                                                   \
        float2 _v;                                                                         \
        _v = ldt(target, base, (r0) + 0, lane, inpos); Pfx##x0 = _v.x; Pfx##y0 = _v.y;     \
        _v = ldt(target, base, (r0) + 1, lane, inpos); Pfx##x1 = _v.x; Pfx##y1 = _v.y;     \
        _v = ldt(target, base, (r0) + 2, lane, inpos); Pfx##x2 = _v.x; Pfx##y2 = _v.y;     \
        _v = ldt(target, base, (r0) + 3, lane, inpos); Pfx##x3 = _v.x; Pfx##y3 = _v.y;     \
        _v = ldt(target, base, (r0) + 4, lane, inpos); Pfx##x4 = _v.x; Pfx##y4 = _v.y;     \
        _v = ldt(target, base, (r0) + 5, lane, inpos); Pfx##x5 = _v.x; Pfx##y5 = _v.y;     \
        _v = ldt(target, base, (r0) + 6, lane, inpos); Pfx##x6 = _v.x; Pfx##y6 = _v.y;     \
        _v = ldt(target, base, (r0) + 7, lane, inpos); Pfx##x7 = _v.x; Pfx##y7 = _v.y;     \
    } while (0)

#define ROWA(Pfx, rr, sx, sy)                                                              \
    row_acc((rr), Pfx##sx, Pfx##sy, flane, inpos, th2min_rev, stp_rev, ca5, sa5,           \
            Pc, Qc, Rc, Sc, Bb, cat, a0, a1, a2, a3, a4)

#define COMPUTEB(Pfx, r0)                                                                  \
    do {                                                                                   \
        ROWA(Pfx, (r0) + 0, x0, y0);                                                       \
        ROWA(Pfx, (r0) + 1, x1, y1);                                                       \
        ROWA(Pfx, (r0) + 2, x2, y2);                                                       \
        ROWA(Pfx, (r0) + 3, x3, y3);                                                       \
        ROWA(Pfx, (r0) + 4, x4, y4);                                                       \
        ROWA(Pfx, (r0) + 5, x5, y5);                                                       \
        ROWA(Pfx, (r0) + 6, x6, y6);                                                       \
        ROWA(Pfx, (r0) + 7, x7, y7);                                                       \
    } while (0)

__global__ __launch_bounds__(256, 4) void posloss_main(
    const float* __restrict__ pred, const float* __restrict__ target,
    float* __restrict__ partials, int B, int nchunks)
{
    const int tid  = threadIdx.x;
    const int lane = tid & 63;
    const int wv   = tid >> 6;
    const int wid  = (blockIdx.x * blockDim.x + tid) >> 6;
    const bool inpos = lane < NPOS;
    const float flane = (float)lane;

    float a0 = 0.f, a1 = 0.f, a2 = 0.f, a3 = 0.f, a4 = 0.f;

    if (wid < nchunks) {
        const int base = wid * CHUNK;
        const int rmax = (B - base) < CHUNK ? (B - base) : CHUNK;

        // ---- issue pred loads ----
        const int prow = base + (lane & 31);
        float r1 = 2.f, r3 = 2.f, r4 = 2.f, r5 = 1.f, al = 0.f;
        if (prow < B) {
            const float* pp = pred + (size_t)prow * 5;
            r1 = pp[0]; r3 = pp[1]; r4 = pp[2]; r5 = pp[3]; al = pp[4];
        }

        // ---- prologue (libm-free): per-row constants in lanes 0..31 ----
        const float sumL = ((r1 + 1.0f) + r3) + r4;
        const float maxL = fmaxf(fmaxf(r1, 1.0f), fmaxf(r3, r4));
        const bool valid = (2.0f * maxL) < sumL;
        const bool c1 = ((r1 + 1.0f) - (r3 + r4)) > 0.0f;
        const bool c2 = (fabsf(r1 - 1.0f) - fabsf(r3 - r4)) >= 0.0f;
        const bool up = valid && c1 && c2;
        const bool lo = valid && (!c1) && (!c2);
        const bool bo = valid && c1 && (!c2);
        const float rdenom = __builtin_amdgcn_rcpf(2.0f * r1);
        const float s34 = r3 + r4, d34 = r3 - r4;
        const float r1sq1 = fmaf(r1, r1, 1.0f);
        float argS = (r1sq1 - s34 * s34) * rdenom;
        float argD = (r1sq1 - d34 * d34) * rdenom;
        argS = (up || bo) ? argS : 0.0f;
        argD = (lo || bo) ? argD : 0.0f;
        argS = fminf(1.0f, fmaxf(-1.0f, argS));
        argD = fminf(1.0f, fmaxf(-1.0f, argD));
        const float acS = acos_poly(argS);
        const float acD = acos_poly(argD);
        float th2min = up ? (-acS) : ((lo || bo) ? acD : 0.0f);
        float th2max = (up || bo) ? acS : (lo ? (TWO_PI_F - acD) : TWO_PI_F);
        if (!valid) { th2min = 0.0f; th2max = TWO_PI_F; }
        const float stp_rev    = (th2max - th2min) * (INV_TWO_PI_F / 59.0f);
        const float th2min_rev = th2min * INV_TWO_PI_F;
        const int cat = (!valid) ? 0 : (up ? 1 : (lo ? 2 : (bo ? 3 : 4)));
        float sal, cal;
        hw_sincos_rev(al * INV_TWO_PI_F, &sal, &cal);
        const float ca5 = r5 * cal, sa5 = r5 * sal;
        // folded k1/k2 algebra: K1c=r1^2+1+r3^2-r4^2, K1m=2r1, A2=2r1r3, B2=2r3
        const float K1c = fmaf(r3, r3, r1sq1) - r4 * r4;
        const float K1m = 2.0f * r1;
        const float A2  = (2.0f * r1) * r3;
        const float B2  = 2.0f * r3;
        const float Pc = K1c + A2;
        const float Qc = K1m + B2;
        const float Rc = K1c - A2;
        const float Sc = K1m - B2;
        const float Bb = 2.0f * B2;

        if (rmax == CHUNK) {
            // ---- burst registers: 32 named scalars, 2 bursts in flight ----
            float Ax0,Ay0,Ax1,Ay1,Ax2,Ay2,Ax3,Ay3,Ax4,Ay4,Ax5,Ay5,Ax6,Ay6,Ax7,Ay7;
            float Bx0,By0,Bx1,By1,Bx2,By2,Bx3,By3,Bx4,By4,Bx5,By5,Bx6,By6,Bx7,By7;
            LOADB(A, 0);
            LOADB(B, 8);
            COMPUTEB(A, 0);
            LOADB(A, 16);
            COMPUTEB(B, 8);
            LOADB(B, 24);
            COMPUTEB(A, 16);
            COMPUTEB(B, 24);
        } else {
            // rare partial-chunk fallback
            for (int rr = 0; rr < rmax; ++rr) {
                const float2 tv = ldt(target, base, rr, lane, inpos);
                row_acc(rr, tv.x, tv.y, flane, inpos, th2min_rev, stp_rev, ca5, sa5,
                        Pc, Qc, Rc, Sc, Bb, cat, a0, a1, a2, a3, a4);
            }
        }
    }

    // ---- wave reduce (64 lanes) ----
    for (int off = 32; off; off >>= 1) {
        a0 += __shfl_xor(a0, off);
        a1 += __shfl_xor(a1, off);
        a2 += __shfl_xor(a2, off);
        a3 += __shfl_xor(a3, off);
        a4 += __shfl_xor(a4, off);
    }
    __shared__ float red[4][5];
    if (lane == 0) {
        red[wv][0] = a0; red[wv][1] = a1; red[wv][2] = a2; red[wv][3] = a3; red[wv][4] = a4;
    }
    __syncthreads();
    if (tid < 5) {
        const float s = ((red[0][tid] + red[1][tid]) + red[2][tid]) + red[3][tid];
        partials[(size_t)tid * gridDim.x + blockIdx.x] = s;
    }
}

__global__ void posloss_reduce(const float* __restrict__ partials, float* __restrict__ out,
                               int nblocks, int B)
{
    const int w = threadIdx.x >> 6, lane = threadIdx.x & 63;
    if (w >= 5) return;
    double s0 = 0.0, s1 = 0.0, s2 = 0.0, s3 = 0.0;
    const float* p = partials + (size_t)w * nblocks;
    for (int k = lane; k + 192 < nblocks; k += 256) {
        s0 += (double)p[k];
        s1 += (double)p[k + 64];
        s2 += (double)p[k + 128];
        s3 += (double)p[k + 192];
    }
    double s = (s0 + s1) + (s2 + s3);
    for (int off = 32; off; off >>= 1) s += __shfl_down(s, off);
    if (lane == 0) out[w] = (float)(s / (double)B);
}

extern "C" void kernel_launch(void* const* d_in, const int* in_sizes, int n_in,
                              void* d_out, int out_size, void* d_ws, size_t ws_size,
                              hipStream_t stream) {
    (void)n_in; (void)out_size; (void)ws_size;
    const float* pred   = (const float*)d_in[0];
    const float* target = (const float*)d_in[1];
    float* out = (float*)d_out;
    float* partials = (float*)d_ws;
    const int B = in_sizes[0] / 5;
    const int nchunks = (B + CHUNK - 1) / CHUNK;
    const int nblocks = 2048;
    posloss_main<<<nblocks, 256, 0, stream>>>(pred, target, partials, B, nchunks);
    posloss_reduce<<<1, 320, 0, stream>>>(partials, out, nblocks, B);
}